// Round 1
// baseline (191.465 us; speedup 1.0000x reference)
//
#include <hip/hip_runtime.h>
#include <hip/hip_bf16.h>

typedef __attribute__((ext_vector_type(4))) float f32x4;
typedef __attribute__((ext_vector_type(2))) float f32x2;
typedef __attribute__((ext_vector_type(8))) short s16x8;
typedef __attribute__((ext_vector_type(4))) unsigned short u16x4;
typedef __attribute__((ext_vector_type(8))) __bf16 bf16x8;

#define HDIM 512
#define SEQ  2048
#define NB   64
#define BM   64
#define BK   32
#define APAD 40   // 32 + 8 pad: row stride 80B, 16B-aligned, spreads LDS banks
#define CCH  16   // context s-chunks per batch row

// round-to-nearest-even fp32 -> bf16 bits
static __device__ __forceinline__ unsigned short f2bf(float f) {
  unsigned u = __float_as_uint(f);
  u += 0x7fffu + ((u >> 16) & 1u);
  return (unsigned short)(u >> 16);
}

static __device__ __forceinline__ f32x4 mfma16(s16x8 a, s16x8 b, f32x4 c) {
  return __builtin_amdgcn_mfma_f32_16x16x32_bf16(
      __builtin_bit_cast(bf16x8, a), __builtin_bit_cast(bf16x8, b), c, 0, 0, 0);
}

#define GLDS16(gp, lp)                                                         \
  __builtin_amdgcn_global_load_lds(                                            \
      (const __attribute__((address_space(1))) void*)(gp),                     \
      (__attribute__((address_space(3))) void*)(lp), 16, 0, 0)

// ---------------- kernel 0a: W1 fp32 -> bf16 (ws) ----------------
__global__ void convert_w1(const float* __restrict__ w1,
                           unsigned short* __restrict__ o) {
  int i = blockIdx.x * 256 + threadIdx.x;   // 65536 threads * 4 elems
  f32x4 v = *(const f32x4*)(w1 + (long)i * 4);
  u16x4 r;
  r.x = f2bf(v.x); r.y = f2bf(v.y); r.z = f2bf(v.z); r.w = f2bf(v.w);
  *(u16x4*)(o + (long)i * 4) = r;
}

// ---------------- kernel 0b: z[b][o] = dec[b]·W2[o] + b2[o] + b1[o] ----------
__global__ void zproj(const float* __restrict__ dec, const float* __restrict__ W2,
                      const float* __restrict__ b1, const float* __restrict__ b2,
                      float* __restrict__ zfull) {
  int b = blockIdx.x, oc = blockIdx.y, tid = threadIdx.x;
  int o = oc * 256 + tid;
  __shared__ float d_s[HDIM];
  d_s[tid] = dec[b * HDIM + tid];
  d_s[tid + 256] = dec[b * HDIM + tid + 256];
  __syncthreads();
  const float* w = W2 + (long)o * HDIM;
  float s = 0.f;
#pragma unroll 4
  for (int k = 0; k < HDIM; k += 4) {
    f32x4 v = *(const f32x4*)(w + k);
    s += v.x * d_s[k] + v.y * d_s[k + 1] + v.z * d_s[k + 2] + v.w * d_s[k + 3];
  }
  zfull[b * HDIM + o] = s + b1[o] + b2[o];
}

// ---------------- kernel 1: fused GEMM + tanh + V-dot -> scores --------------
// C[m][n] = sum_k enc[m][k] * W1[n][k]; scores[m] = sum_n tanh(C+z[b][n])*V[n] + bv
__global__ __launch_bounds__(512, 2)
void gemm_scores(const float* __restrict__ enc, const unsigned short* __restrict__ w1b,
                 const float* __restrict__ zfull, const float* __restrict__ V,
                 const float* __restrict__ bv, float* __restrict__ scores) {
  __shared__ unsigned short Abuf[2][BM][APAD];    // 10 KiB
  __shared__ unsigned short Bbuf[2][HDIM * BK];   // 64 KiB
  __shared__ float zbuf[HDIM];                    // 2 KiB
  __shared__ float vbuf[HDIM];                    // 2 KiB
  __shared__ float red[8][BM];                    // 2 KiB

  const int tid = threadIdx.x;
  const int wid = tid >> 6;
  const int lane = tid & 63;
  const long m0 = (long)blockIdx.x * BM;
  const int b = (int)(m0 >> 11);   // 2048 rows per batch; BM=64 never crosses

  zbuf[tid] = zfull[b * HDIM + tid];
  vbuf[tid] = V[tid];

  const float* Ablk = enc + m0 * HDIM;
  const int am = tid >> 3, akq = tid & 7;

  f32x4 acc[4][4] = {};

  auto stage_b = [&](int buf, int kk) {
#pragma unroll
    for (int r = 0; r < 4; ++r) {
      int j = r * 512 + tid;  // 16B chunk index; per-wave linear LDS dest
      const unsigned short* g = w1b + (long)(j >> 2) * HDIM + kk * BK + (j & 3) * 8;
      GLDS16(g, (char*)&Bbuf[buf][0] + j * 16);
    }
  };

  // prologue: stage k-step 0
  f32x4 areg = *(const f32x4*)(Ablk + (long)am * HDIM + akq * 4);
  stage_b(0, 0);
  {
    u16x4 p;
    p.x = f2bf(areg.x); p.y = f2bf(areg.y); p.z = f2bf(areg.z); p.w = f2bf(areg.w);
    *(u16x4*)&Abuf[0][am][akq * 4] = p;
  }
  __syncthreads();

  const int r4 = lane >> 4, c15 = lane & 15;

  for (int kk = 0; kk < 16; ++kk) {
    const int cur = kk & 1, nxt = cur ^ 1;
    if (kk < 15) {
      areg = *(const f32x4*)(Ablk + (long)am * HDIM + (kk + 1) * BK + akq * 4);
      stage_b(nxt, kk + 1);
    }
    s16x8 af[4], bfr[4];
    const char* Ab = (const char*)&Abuf[cur][0][0];
    const char* Bb = (const char*)&Bbuf[cur][0];
#pragma unroll
    for (int mf = 0; mf < 4; ++mf)
      af[mf] = *(const s16x8*)(Ab + (mf * 16 + c15) * (APAD * 2) + r4 * 16);
#pragma unroll
    for (int nf = 0; nf < 4; ++nf)
      bfr[nf] = *(const s16x8*)(Bb + (wid * 64 + nf * 16 + c15) * (BK * 2) + r4 * 16);
#pragma unroll
    for (int mf = 0; mf < 4; ++mf)
#pragma unroll
      for (int nf = 0; nf < 4; ++nf)
        acc[mf][nf] = mfma16(af[mf], bfr[nf], acc[mf][nf]);
    if (kk < 15) {
      u16x4 p;
      p.x = f2bf(areg.x); p.y = f2bf(areg.y); p.z = f2bf(areg.z); p.w = f2bf(areg.w);
      *(u16x4*)&Abuf[nxt][am][akq * 4] = p;
    }
    __syncthreads();
  }

  // epilogue: scores[m] = sum_n tanh(acc + z[n]) * V[n]
  // C/D layout (16x16x32): col = lane&15, row = (lane>>4)*4 + j   [m89/m91]
#pragma unroll
  for (int mf = 0; mf < 4; ++mf) {
#pragma unroll
    for (int j = 0; j < 4; ++j) {
      float s = 0.f;
#pragma unroll
      for (int nf = 0; nf < 4; ++nf) {
        const int n = wid * 64 + nf * 16 + c15;
        float x = acc[mf][nf][j] + zbuf[n];
        float e = __expf(2.f * x);
        float t = 1.f - 2.f * __builtin_amdgcn_rcpf(e + 1.f);  // tanh(x)
        s += t * vbuf[n];
      }
      s += __shfl_xor(s, 1); s += __shfl_xor(s, 2);
      s += __shfl_xor(s, 4); s += __shfl_xor(s, 8);
      if (c15 == 0) red[wid][mf * 16 + r4 * 4 + j] = s;
    }
  }
  __syncthreads();
  if (tid < BM) {
    float s = 0.f;
#pragma unroll
    for (int w = 0; w < 8; ++w) s += red[w][tid];
    scores[m0 + tid] = s + bv[0];
  }
}

// ---------------- kernel 2: per-batch softmax over S=2048 (in place) ---------
__global__ void softmax_k(const float* __restrict__ scores, float* __restrict__ attn) {
  int b = blockIdx.x, tid = threadIdx.x;
  const float* s = scores + (long)b * SEQ;
  float v[8];
  float mx = -1e30f;
#pragma unroll
  for (int i = 0; i < 8; ++i) { v[i] = s[i * 256 + tid]; mx = fmaxf(mx, v[i]); }
  for (int off = 1; off < 64; off <<= 1) mx = fmaxf(mx, __shfl_xor(mx, off));
  __shared__ float redm[4];
  __shared__ float redz[4];
  int w = tid >> 6, ln = tid & 63;
  if (ln == 0) redm[w] = mx;
  __syncthreads();
  mx = fmaxf(fmaxf(redm[0], redm[1]), fmaxf(redm[2], redm[3]));
  float z = 0.f;
#pragma unroll
  for (int i = 0; i < 8; ++i) { v[i] = __expf(v[i] - mx); z += v[i]; }
  for (int off = 1; off < 64; off <<= 1) z += __shfl_xor(z, off);
  if (ln == 0) redz[w] = z;
  __syncthreads();
  z = redz[0] + redz[1] + redz[2] + redz[3];
  float inv = 1.f / z;
#pragma unroll
  for (int i = 0; i < 8; ++i) attn[(long)b * SEQ + i * 256 + tid] = v[i] * inv;
}

// ---------------- kernel 3: partial context over s-chunks --------------------
__global__ void ctx_partial(const float* __restrict__ enc, const float* __restrict__ attn,
                            float* __restrict__ partial) {
  int b = blockIdx.x, c = blockIdx.y, tid = threadIdx.x;
  __shared__ float a_s[SEQ / CCH];
  if (tid < SEQ / CCH) a_s[tid] = attn[(long)b * SEQ + c * (SEQ / CCH) + tid];
  __syncthreads();
  const float* e = enc + ((long)b * SEQ + (long)c * (SEQ / CCH)) * HDIM + tid * 2;
  float ax = 0.f, ay = 0.f;
#pragma unroll 4
  for (int s = 0; s < SEQ / CCH; ++s) {
    f32x2 v = *(const f32x2*)(e + (long)s * HDIM);
    float a = a_s[s];
    ax += a * v.x; ay += a * v.y;
  }
  f32x2 r; r.x = ax; r.y = ay;
  *(f32x2*)(partial + ((long)(b * CCH + c) * HDIM) + tid * 2) = r;
}

// ---------------- kernel 4: reduce partials -> context -----------------------
__global__ void ctx_reduce(const float* __restrict__ partial, float* __restrict__ ctx) {
  int i = blockIdx.x * 256 + threadIdx.x;   // 32768 = 64*512
  int b = i >> 9, h = i & 511;
  const float* p = partial + (long)b * CCH * HDIM + h;
  float s = 0.f;
#pragma unroll
  for (int c = 0; c < CCH; ++c) s += p[c * HDIM];
  ctx[i] = s;
}

extern "C" void kernel_launch(void* const* d_in, const int* in_sizes, int n_in,
                              void* d_out, int out_size, void* d_ws, size_t ws_size,
                              hipStream_t stream) {
  const float* enc = (const float*)d_in[0];
  const float* dec = (const float*)d_in[1];
  const float* W1  = (const float*)d_in[2];
  const float* b1  = (const float*)d_in[3];
  const float* W2  = (const float*)d_in[4];
  const float* b2  = (const float*)d_in[5];
  const float* V   = (const float*)d_in[6];
  const float* bv  = (const float*)d_in[7];

  float* out  = (float*)d_out;
  float* ctx  = out;                       // 64*512
  float* attn = out + NB * HDIM;           // 64*2048 (also holds raw scores first)

  char* ws = (char*)d_ws;
  unsigned short* w1b = (unsigned short*)ws;                 // 512 KiB
  float* zfull   = (float*)(ws + 524288);                    // 128 KiB
  float* partial = (float*)(ws + 524288 + 131072);           // 2 MiB
  (void)in_sizes; (void)n_in; (void)out_size; (void)ws_size;

  convert_w1<<<256, 256, 0, stream>>>(W1, w1b);
  zproj<<<dim3(NB, 2), 256, 0, stream>>>(dec, W2, b1, b2, zfull);
  gemm_scores<<<(NB * SEQ) / BM, 512, 0, stream>>>(enc, w1b, zfull, V, bv, attn);
  softmax_k<<<NB, 256, 0, stream>>>(attn, attn);
  ctx_partial<<<dim3(NB, CCH), 256, 0, stream>>>(enc, attn, partial);
  ctx_reduce<<<128, 256, 0, stream>>>(partial, ctx);
}

// Round 2
// 175.292 us; speedup vs baseline: 1.0923x; 1.0923x over previous
//
#include <hip/hip_runtime.h>
#include <hip/hip_bf16.h>

typedef __attribute__((ext_vector_type(4))) float f32x4;
typedef __attribute__((ext_vector_type(2))) float f32x2;
typedef __attribute__((ext_vector_type(8))) short s16x8;
typedef __attribute__((ext_vector_type(4))) unsigned short u16x4;
typedef __attribute__((ext_vector_type(8))) __bf16 bf16x8;

#define HDIM 512
#define SEQ  2048
#define NB   64
#define BM   64
#define BK   32
#define APAD 40   // A row stride 80B: bank-start period 8 over rows -> 2-way (free)
#define CCH  16

// round-to-nearest-even fp32 -> bf16 bits
static __device__ __forceinline__ unsigned short f2bf(float f) {
  unsigned u = __float_as_uint(f);
  u += 0x7fffu + ((u >> 16) & 1u);
  return (unsigned short)(u >> 16);
}

static __device__ __forceinline__ f32x4 mfma16(s16x8 a, s16x8 b, f32x4 c) {
  return __builtin_amdgcn_mfma_f32_16x16x32_bf16(
      __builtin_bit_cast(bf16x8, a), __builtin_bit_cast(bf16x8, b), c, 0, 0, 0);
}

#define GLDS16(gp, lp)                                                         \
  __builtin_amdgcn_global_load_lds(                                            \
      (const __attribute__((address_space(1))) void*)(gp),                     \
      (__attribute__((address_space(3))) void*)(lp), 16, 0, 0)

// ---------------- kernel 0a: W1 fp32 -> bf16, k-step-major + XOR-swizzled ----
// Layout: 16B chunk id = kk*2048 + c, c = n*4 + p, p = q ^ ((n>>1)&3),
// holds W1[n][kk*32 + q*8 .. +8] as bf16. Staging then copies LINEARLY
// (perfect coalescing + linear LDS dest), and the swizzle kills the 8-way
// bank conflict on B-fragment ds_read_b128 (bank-start {n&1, p} -> 2-way).
__global__ void convert_w1(const float* __restrict__ w1,
                           unsigned short* __restrict__ o) {
  int id = blockIdx.x * 256 + threadIdx.x;   // 32768 chunks of 16B
  int kk = id >> 11, c = id & 2047;
  int n = c >> 2;
  int q = (c & 3) ^ ((n >> 1) & 3);
  const float* src = w1 + (long)n * HDIM + kk * BK + q * 8;
  f32x4 v0 = *(const f32x4*)src;
  f32x4 v1 = *(const f32x4*)(src + 4);
  u16x4 a, b;
  a.x = f2bf(v0.x); a.y = f2bf(v0.y); a.z = f2bf(v0.z); a.w = f2bf(v0.w);
  b.x = f2bf(v1.x); b.y = f2bf(v1.y); b.z = f2bf(v1.z); b.w = f2bf(v1.w);
  unsigned short* dst = o + (long)id * 8;
  *(u16x4*)dst = a;
  *(u16x4*)(dst + 4) = b;
}

// ---------------- kernel 0b: z[b][o] = dec[b]·W2[o] + b2[o] + b1[o] ----------
__global__ void zproj(const float* __restrict__ dec, const float* __restrict__ W2,
                      const float* __restrict__ b1, const float* __restrict__ b2,
                      float* __restrict__ zfull) {
  int b = blockIdx.x, oc = blockIdx.y, tid = threadIdx.x;
  int o = oc * 256 + tid;
  __shared__ float d_s[HDIM];
  d_s[tid] = dec[b * HDIM + tid];
  d_s[tid + 256] = dec[b * HDIM + tid + 256];
  __syncthreads();
  const float* w = W2 + (long)o * HDIM;
  float s = 0.f;
#pragma unroll 4
  for (int k = 0; k < HDIM; k += 4) {
    f32x4 v = *(const f32x4*)(w + k);
    s += v.x * d_s[k] + v.y * d_s[k + 1] + v.z * d_s[k + 2] + v.w * d_s[k + 3];
  }
  zfull[b * HDIM + o] = s + b1[o] + b2[o];
}

// ---------------- kernel 1: fused GEMM + tanh + V-dot -> scores --------------
__global__ __launch_bounds__(512, 4)
void gemm_scores(const float* __restrict__ enc, const unsigned short* __restrict__ w1b,
                 const float* __restrict__ zfull, const float* __restrict__ V,
                 const float* __restrict__ bv, float* __restrict__ scores) {
  __shared__ unsigned short Bbuf[2][HDIM * BK];   // 64 KiB (32 KiB per buffer)
  __shared__ unsigned short Abuf[2][BM][APAD];    // 10 KiB (5120 B per buffer)
  __shared__ float zbuf[HDIM];                    // 2 KiB
  __shared__ float vbuf[HDIM];                    // 2 KiB
  __shared__ float red[8][BM];                    // 2 KiB -> total 81920 B, 2 blk/CU

  const int tid = threadIdx.x;
  const int wid = tid >> 6;
  const int lane = tid & 63;
  const long m0 = (long)blockIdx.x * BM;
  const int b = (int)(m0 >> 11);

  zbuf[tid] = zfull[b * HDIM + tid];
  vbuf[tid] = V[tid];

  // A global: each thread owns one 16B chunk of one row per k-step
  const int am = tid >> 3, akq = tid & 7;
  const float* ap = enc + (m0 + am) * HDIM + akq * 4;

  const int r4 = lane >> 4, c15 = lane & 15;

  // per-thread LDS read bases (bytes); all loop variation is immediate offsets
  const char* Ab = (const char*)&Abuf[0][0][0];
  const char* Bb = (const char*)&Bbuf[0][0];
  const int sA = c15 * (APAD * 2) + r4 * 16;                   // + mf*16*80 + cur*5120
  const int qsw = r4 ^ ((c15 >> 1) & 3);                       // swizzled quad
  const int sB = (wid * 64 + c15) * 64 + qsw * 16;             // + nf*1024 + cur*32768

  // staging: 4 linear 16B chunks per thread per k-step
  const unsigned short* sp = w1b + (long)tid * 8;              // + r*4096 + kk*16384 (ushorts)
  char* Bd = (char*)&Bbuf[0][0];                               // dest + r*8192 + tid*16 + buf*32768
  char* Ad = (char*)&Abuf[0][0][0] + am * (APAD * 2) + akq * 8;

  f32x4 acc[4][4] = {};

  // ---- prologue: stage k-step 0 into buffer 0 ----
  f32x4 areg = *(const f32x4*)ap;
#pragma unroll
  for (int r = 0; r < 4; ++r)
    GLDS16(sp + r * 4096, Bd + r * 8192 + tid * 16);
  {
    u16x4 p;
    p.x = f2bf(areg.x); p.y = f2bf(areg.y); p.z = f2bf(areg.z); p.w = f2bf(areg.w);
    *(u16x4*)Ad = p;
  }
  __syncthreads();

#pragma unroll
  for (int kk = 0; kk < 16; ++kk) {
    const int cur = kk & 1;
    if (kk < 15) {
      areg = *(const f32x4*)(ap + (kk + 1) * BK);
#pragma unroll
      for (int r = 0; r < 4; ++r)
        GLDS16(sp + (long)(kk + 1) * 16384 + r * 4096,
               Bd + (cur ^ 1) * 32768 + r * 8192 + tid * 16);
    }
    s16x8 af[4], bfr[4];
#pragma unroll
    for (int mf = 0; mf < 4; ++mf)
      af[mf] = *(const s16x8*)(Ab + cur * 5120 + mf * 16 * (APAD * 2) + sA);
#pragma unroll
    for (int nf = 0; nf < 4; ++nf)
      bfr[nf] = *(const s16x8*)(Bb + cur * 32768 + nf * 1024 + sB);
#pragma unroll
    for (int mf = 0; mf < 4; ++mf)
#pragma unroll
      for (int nf = 0; nf < 4; ++nf)
        acc[mf][nf] = mfma16(af[mf], bfr[nf], acc[mf][nf]);
    if (kk < 15) {
      u16x4 p;
      p.x = f2bf(areg.x); p.y = f2bf(areg.y); p.z = f2bf(areg.z); p.w = f2bf(areg.w);
      *(u16x4*)(Ad + (cur ^ 1) * 5120) = p;
    }
    __syncthreads();
  }

  // ---- epilogue: scores[m] = sum_n tanh(acc + z[n]) * V[n] + bv ----
  // C/D layout (16x16x32): col = lane&15, row = (lane>>4)*4 + j   [m89/m91]
#pragma unroll
  for (int mf = 0; mf < 4; ++mf) {
#pragma unroll
    for (int j = 0; j < 4; ++j) {
      float s = 0.f;
#pragma unroll
      for (int nf = 0; nf < 4; ++nf) {
        const int n = wid * 64 + nf * 16 + c15;
        float x = acc[mf][nf][j] + zbuf[n];
        float e = __expf(2.f * x);
        float t = 1.f - 2.f * __builtin_amdgcn_rcpf(e + 1.f);  // tanh(x)
        s += t * vbuf[n];
      }
      s += __shfl_xor(s, 1); s += __shfl_xor(s, 2);
      s += __shfl_xor(s, 4); s += __shfl_xor(s, 8);
      if (c15 == 0) red[wid][mf * 16 + r4 * 4 + j] = s;
    }
  }
  __syncthreads();
  if (tid < BM) {
    float s = 0.f;
#pragma unroll
    for (int w = 0; w < 8; ++w) s += red[w][tid];
    scores[m0 + tid] = s + bv[0];
  }
}

// ---------------- kernel 2: per-batch softmax over S=2048 (in place) ---------
__global__ void softmax_k(const float* __restrict__ scores, float* __restrict__ attn) {
  int b = blockIdx.x, tid = threadIdx.x;
  const float* s = scores + (long)b * SEQ;
  float v[8];
  float mx = -1e30f;
#pragma unroll
  for (int i = 0; i < 8; ++i) { v[i] = s[i * 256 + tid]; mx = fmaxf(mx, v[i]); }
  for (int off = 1; off < 64; off <<= 1) mx = fmaxf(mx, __shfl_xor(mx, off));
  __shared__ float redm[4];
  __shared__ float redz[4];
  int w = tid >> 6, ln = tid & 63;
  if (ln == 0) redm[w] = mx;
  __syncthreads();
  mx = fmaxf(fmaxf(redm[0], redm[1]), fmaxf(redm[2], redm[3]));
  float z = 0.f;
#pragma unroll
  for (int i = 0; i < 8; ++i) { v[i] = __expf(v[i] - mx); z += v[i]; }
  for (int off = 1; off < 64; off <<= 1) z += __shfl_xor(z, off);
  if (ln == 0) redz[w] = z;
  __syncthreads();
  z = redz[0] + redz[1] + redz[2] + redz[3];
  float inv = 1.f / z;
#pragma unroll
  for (int i = 0; i < 8; ++i) attn[(long)b * SEQ + i * 256 + tid] = v[i] * inv;
}

// ---------------- kernel 3: partial context over s-chunks --------------------
__global__ void ctx_partial(const float* __restrict__ enc, const float* __restrict__ attn,
                            float* __restrict__ partial) {
  int b = blockIdx.x, c = blockIdx.y, tid = threadIdx.x;
  __shared__ float a_s[SEQ / CCH];
  if (tid < SEQ / CCH) a_s[tid] = attn[(long)b * SEQ + c * (SEQ / CCH) + tid];
  __syncthreads();
  const float* e = enc + ((long)b * SEQ + (long)c * (SEQ / CCH)) * HDIM + tid * 2;
  float ax = 0.f, ay = 0.f;
#pragma unroll 4
  for (int s = 0; s < SEQ / CCH; ++s) {
    f32x2 v = *(const f32x2*)(e + (long)s * HDIM);
    float a = a_s[s];
    ax += a * v.x; ay += a * v.y;
  }
  f32x2 r; r.x = ax; r.y = ay;
  *(f32x2*)(partial + ((long)(b * CCH + c) * HDIM) + tid * 2) = r;
}

// ---------------- kernel 4: reduce partials -> context -----------------------
__global__ void ctx_reduce(const float* __restrict__ partial, float* __restrict__ ctx) {
  int i = blockIdx.x * 256 + threadIdx.x;   // 32768 = 64*512
  int b = i >> 9, h = i & 511;
  const float* p = partial + (long)b * CCH * HDIM + h;
  float s = 0.f;
#pragma unroll
  for (int c = 0; c < CCH; ++c) s += p[c * HDIM];
  ctx[i] = s;
}

extern "C" void kernel_launch(void* const* d_in, const int* in_sizes, int n_in,
                              void* d_out, int out_size, void* d_ws, size_t ws_size,
                              hipStream_t stream) {
  const float* enc = (const float*)d_in[0];
  const float* dec = (const float*)d_in[1];
  const float* W1  = (const float*)d_in[2];
  const float* b1  = (const float*)d_in[3];
  const float* W2  = (const float*)d_in[4];
  const float* b2  = (const float*)d_in[5];
  const float* V   = (const float*)d_in[6];
  const float* bv  = (const float*)d_in[7];

  float* out  = (float*)d_out;
  float* ctx  = out;                       // 64*512
  float* attn = out + NB * HDIM;           // 64*2048 (raw scores first, softmaxed in place)

  char* ws = (char*)d_ws;
  unsigned short* w1b = (unsigned short*)ws;                 // 512 KiB (swizzled)
  float* zfull   = (float*)(ws + 524288);                    // 128 KiB
  float* partial = (float*)(ws + 524288 + 131072);           // 2 MiB
  (void)in_sizes; (void)n_in; (void)out_size; (void)ws_size;

  convert_w1<<<128, 256, 0, stream>>>(W1, w1b);
  zproj<<<dim3(NB, 2), 256, 0, stream>>>(dec, W2, b1, b2, zfull);
  gemm_scores<<<(NB * SEQ) / BM, 512, 0, stream>>>(enc, w1b, zfull, V, bv, attn);
  softmax_k<<<NB, 256, 0, stream>>>(attn, attn);
  ctx_partial<<<dim3(NB, CCH), 256, 0, stream>>>(enc, attn, partial);
  ctx_reduce<<<128, 256, 0, stream>>>(partial, ctx);
}